// Round 10
// baseline (795.016 us; speedup 1.0000x reference)
//
#include <hip/hip_runtime.h>
#include <math.h>

#define HH 160
#define WW 160
#define HWSZ 25600
#define TR 14
#define TC 22
#define NSLOT 308   // TR*TC tile slots, margin +-3 around 16x8 px tile
#define NBLK 800    // grid blocks; <= 4 blocks/CU x 256 CU -> co-resident

typedef __attribute__((ext_vector_type(8))) short short8;
typedef __attribute__((ext_vector_type(4))) short short4v;
typedef __attribute__((ext_vector_type(8))) _Float16 half8;
typedef __attribute__((ext_vector_type(2))) _Float16 half2v;
typedef __attribute__((ext_vector_type(4))) float f32x4;
typedef __attribute__((ext_vector_type(16))) float f32x16;
typedef __attribute__((ext_vector_type(2))) unsigned int uint2v;

__device__ __forceinline__ short f2h(float f) {
  union { _Float16 h; short s; } u; u.h = (_Float16)f; return u.s;
}
__device__ __forceinline__ float h2f(short s) {
  union { _Float16 h; short s; } u; u.s = s; return (float)u.h;
}
__device__ __forceinline__ half2v bcast_h(short s) {
  unsigned int x = (unsigned short)s; x |= x << 16;
  union { unsigned int u; half2v h; } v; v.u = x; return v.h;
}

// Software grid barrier: valid because the full 800-block grid is co-resident
// (LDS 39424 B -> 4 blocks/CU x 256 CU = 1024 slots >= 800; launch_bounds
// enforces the occupancy). Device-scope atomics + fences per Guideline 16.
__device__ __forceinline__ void gridbar(int* bar, int id) {
  __threadfence();     // release: drain this block's global writes
  __syncthreads();
  if (threadIdx.x == 0) {
    __hip_atomic_fetch_add(&bar[id], 1, __ATOMIC_ACQ_REL,
                           __HIP_MEMORY_SCOPE_AGENT);
    while (__hip_atomic_load(&bar[id], __ATOMIC_ACQUIRE,
                             __HIP_MEMORY_SCOPE_AGENT) < NBLK)
      __builtin_amdgcn_s_sleep(2);
  }
  __syncthreads();
  __threadfence();     // acquire: invalidate stale cache lines
}

// ---------------------------------------------------------------------------
// dcn body (r8 verbatim): offset-conv (27ch) + modulated deform conv + BN
// + optional residual + GELU from one staged tile. 256 thr / 4 waves,
// all GEMMs 32x32x16; om D-col = owner pixel lane; permlane32_swap for the
// complementary oc half; A-frags direct from global (L1/L2-resident);
// ONE __syncthreads per invocation.
__device__ __forceinline__ void dcn_body(
    short* xt, int t, int bix, int biy, int biz,
    const short* __restrict__ xcl,     // [B][HW][64] f16 NHWC
    const short* __restrict__ who,     // om weights  [kk36][hi2][oc32][j8]
    const float* __restrict__ bias_om, // 27
    const short* __restrict__ whd,     // dcn weights [tap][s][ot][hi][oc][j]
    const float* __restrict__ scale, const float* __restrict__ shift,
    const short* __restrict__ id_cl,   // f16 NHWC residual or null
    short* __restrict__ out_cl,        // f16 NHWC (layer 1) or null
    float* __restrict__ out_f32) {     // f32 NCHW (layer 2) or null
  int x0 = bix * 16, y0 = biy * 8, b = biz;
  int w = t >> 6, lane = t & 63, m = lane & 15;
  int hi = lane >> 5, p31 = lane & 31;
  int ybase = y0 - 3, xbase = x0 - 3;

  // ---- stage tile (coalesced b128 copies) ----
  const short* xb = xcl + (size_t)b * HWSZ * 64;
  for (int i = t; i < NSLOT * 8; i += 256) {
    int slot = i >> 3, g = i & 7;
    int ty = slot / TC, tx = slot - ty * TC;
    int gy = ybase + ty, gx = xbase + tx;
    short8 v = {};
    if (gy >= 0 && gy < HH && gx >= 0 && gx < WW)
      v = *(const short8*)&xb[(gy * WW + gx) * 64 + g * 8];
    *(short8*)&xt[slot * 64 + ((g ^ (slot & 7)) << 3)] = v;
  }
  __syncthreads();  // xt visible -- the ONLY intra-phase barrier

  // ---- om GEMM (32x32x16): 27 oc x 32 px per wave, D col = own pixel ----
  union { short s[32]; unsigned int u[16]; } omr;
  {
    f32x16 oacc = {};
#pragma unroll
    for (int k9 = 0; k9 < 9; k9++) {
      int ki = k9 / 3, kj = k9 - ki * 3;
      int slotb = (w * 2 + (p31 >> 4) + ki + 2) * TC + ((p31 & 15) + kj + 2);
#pragma unroll
      for (int s = 0; s < 4; s++) {
        int g = s * 2 + hi;
        union { short8 s8; half8 h; } A, B;
        B.s8 = *(const short8*)&xt[slotb * 64 + ((g ^ (slotb & 7)) << 3)];
        A.s8 = *(const short8*)&who[((k9 * 4 + s) * 64 + lane) * 8];
        oacc = __builtin_amdgcn_mfma_f32_32x32x16_f16(A.h, B.h, oacc, 0, 0, 0);
      }
    }
#pragma unroll
    for (int j = 0; j < 8; j++) {
      int c0 = 2 * (j & 1) + 8 * (j >> 1);  // channel pair base for hi=0
      int oc0 = c0 + 4 * hi;                // this lane's oc for r=2j
      float b0 = (oc0 < 27) ? bias_om[oc0] : 0.f;
      float b1 = (oc0 + 1 < 27) ? bias_om[oc0 + 1] : 0.f;
      union { unsigned int u; short s2[2]; } pk;
      pk.s2[0] = f2h(oacc[2 * j] + b0);
      pk.s2[1] = f2h(oacc[2 * j + 1] + b1);
      uint2v sw = __builtin_amdgcn_permlane32_swap(pk.u, pk.u, false, false);
      omr.u[c0 >> 1]       = sw[0];
      omr.u[(c0 + 4) >> 1] = sw[1];
    }
  }

  int y = y0 + w * 2 + (p31 >> 4), x = x0 + m;

  // hoist layer-2 residual load above the tap loop (hides HBM latency)
  short4v ivs[8];
  if (out_f32) {
    size_t pbase = ((size_t)b * HWSZ + y * WW + x) * 64;
#pragma unroll
    for (int ot = 0; ot < 2; ot++)
#pragma unroll
      for (int blk = 0; blk < 4; blk++)
        ivs[ot * 4 + blk] =
            *(const short4v*)&id_cl[pbase + ot * 32 + blk * 8 + hi * 4];
  }

  // ---- main GEMM (32x32x16): 64 oc x 32 px/wave, K=576; barrier-free ----
  f32x16 acc0 = {}, acc1 = {};
#pragma unroll
  for (int k = 0; k < 9; ++k) {
    // inline meta for this lane's pixel (verbatim formulas)
    float dy = h2f(omr.s[2 * k]);
    float dx = h2f(omr.s[2 * k + 1]);
    float ml = h2f(omr.s[18 + k]);
    float msk = 1.f / (1.f + __expf(-ml));
    int ki = k / 3, kj = k - ki * 3;
    float py  = (float)(y - 1 + ki) + dy;
    float pxf = (float)(x - 1 + kj) + dx;
    float fy = floorf(py), fx = floorf(pxf);
    float ly = py - fy, lx = pxf - fx;
    int yi0 = (int)fy, xi0 = (int)fx;
    bool vy0 = (yi0 >= 0) & (yi0 < HH), vy1 = (yi0 + 1 >= 0) & (yi0 + 1 < HH);
    bool vx0 = (xi0 >= 0) & (xi0 < WW), vx1 = (xi0 + 1 >= 0) & (xi0 + 1 < WW);
    int ty0 = min(max(yi0 - ybase, 0), TR - 2);
    int tx0 = min(max(xi0 - xbase, 0), TC - 2);
    int p00 = ty0 * TC + tx0;
    half2v w00 = bcast_h(f2h((vy0 & vx0) ? (1.f - ly) * (1.f - lx) * msk : 0.f));
    half2v w01 = bcast_h(f2h((vy0 & vx1) ? (1.f - ly) * lx * msk : 0.f));
    half2v w10 = bcast_h(f2h((vy1 & vx0) ? ly * (1.f - lx) * msk : 0.f));
    half2v w11 = bcast_h(f2h((vy1 & vx1) ? ly * lx * msk : 0.f));
    int s00 = p00, s01 = p00 + 1, s10 = p00 + TC, s11 = p00 + TC + 1;
#pragma unroll
    for (int s = 0; s < 4; s++) {
      int g = s * 2 + hi;  // 16B ch-group this lane consumes for slice s
      union { short8 s8; half2v h[4]; } c00, c01, c10, c11, bb;
      c00.s8 = *(const short8*)&xt[s00 * 64 + ((g ^ (s00 & 7)) << 3)];
      c01.s8 = *(const short8*)&xt[s01 * 64 + ((g ^ (s01 & 7)) << 3)];
      c10.s8 = *(const short8*)&xt[s10 * 64 + ((g ^ (s10 & 7)) << 3)];
      c11.s8 = *(const short8*)&xt[s11 * 64 + ((g ^ (s11 & 7)) << 3)];
#pragma unroll
      for (int d = 0; d < 4; d++)
        bb.h[d] = c00.h[d] * w00 + c01.h[d] * w01 + c10.h[d] * w10 +
                  c11.h[d] * w11;
      // A-frags straight from global: 1KB contiguous per wave read,
      // whd (72 KB) is L1/L2-resident and shared by all blocks
      const short* ap = whd + k * 4096 + s * 1024 + lane * 8;
      short8 a0 = *(const short8*)ap;
      short8 a1 = *(const short8*)(ap + 512);
      union { short8 s8; half8 h8; } B, A0, A1;
      B.s8 = bb.s8; A0.s8 = a0; A1.s8 = a1;
      acc0 = __builtin_amdgcn_mfma_f32_32x32x16_f16(A0.h8, B.h8, acc0, 0, 0, 0);
      acc1 = __builtin_amdgcn_mfma_f32_32x32x16_f16(A1.h8, B.h8, acc1, 0, 0, 0);
    }
  }

  // ---- epilogue ----
  // D layout (32x32): col px = lane&31; row oc_in_tile = (r&3)+8*(r>>2)+4*hi
  if (out_f32) {  // layer 2: BN + residual (f16 NHWC) + GELU -> f32 NCHW
#pragma unroll
    for (int ot = 0; ot < 2; ot++) {
#pragma unroll
      for (int r = 0; r < 16; r++) {
        int oc = ot * 32 + (r & 3) + 8 * (r >> 2) + 4 * hi;
        float a = ot ? acc1[r] : acc0[r];
        size_t idx = ((size_t)(b * 64 + oc)) * HWSZ + y * WW + x;
        float v = a * scale[oc] + shift[oc] + h2f(ivs[ot * 4 + (r >> 2)][r & 3]);
        v = 0.5f * v * (1.f + erff(v * 0.70710678118654752f));
        out_f32[idx] = v;
      }
    }
  } else {  // layer 1: BN + GELU -> f16 NHWC
    size_t base = ((size_t)b * HWSZ + y * WW + x) * 64;
#pragma unroll
    for (int ot = 0; ot < 2; ot++) {
#pragma unroll
      for (int blk = 0; blk < 4; blk++) {
        short4v pv;
#pragma unroll
        for (int rr = 0; rr < 4; rr++) {
          int r = blk * 4 + rr;
          int oc = ot * 32 + blk * 8 + hi * 4 + rr;
          float a = ot ? acc1[r] : acc0[r];
          float v = a * scale[oc] + shift[oc];
          v = 0.5f * v * (1.f + erff(v * 0.70710678118654752f));
          pv[rr] = f2h(v);
        }
        *(short4v*)&out_cl[base + ot * 32 + blk * 8 + hi * 4] = pv;
      }
    }
  }
}

// ---------------------------------------------------------------------------
// fused_all: ONE dispatch for the whole block.
//   phase 0: x f32 NCHW -> f16 NHWC transpose (2 units/block over 800
//            blocks) + BN fold + weight reorders (low-index threads)
//   gridbar -> phase 1: layer-1 dcn -> gridbar -> phase 2: layer-2 dcn.
// Removes two kernel launches and the thin 1664-block pre dispatch.
__global__ __launch_bounds__(256, 4) void fused_all(
    const float* __restrict__ x,
    const float* __restrict__ g1, const float* __restrict__ b1,
    const float* __restrict__ m1, const float* __restrict__ v1,
    const float* __restrict__ g2, const float* __restrict__ b2,
    const float* __restrict__ m2, const float* __restrict__ v2,
    const float* __restrict__ wd1, const float* __restrict__ wd2,
    const float* __restrict__ wo1, const float* __restrict__ wo2,
    const float* __restrict__ b_om1, const float* __restrict__ b_om2,
    float* __restrict__ sc, short* __restrict__ w1h, short* __restrict__ w2h,
    short* __restrict__ wo1h, short* __restrict__ wo2h,
    short* __restrict__ x_cl, short* __restrict__ o1_cl,
    float* __restrict__ outp, int* bar) {
  __shared__ short xt[NSLOT * 64];  // 39424 B (transpose tmp aliased inside)

  int t = threadIdx.x;
  int bf = ((int)blockIdx.z * 20 + (int)blockIdx.y) * 10 + (int)blockIdx.x;

  // ---- phase 0a: transpose two 64-px units ----
  short (*tmp)[72] = (short(*)[72])xt;
#pragma unroll
  for (int uu = 0; uu < 2; ++uu) {
    int u = bf * 2 + uu;
    int b = u / 400, p0 = (u - b * 400) * 64;
    const float* xb = x + (size_t)b * 64 * HWSZ;
    for (int i = t; i < 4096; i += 256) {
      int c = i >> 6, p = i & 63;
      tmp[p][c] = f2h(xb[c * HWSZ + p0 + p]);
    }
    __syncthreads();
    short* ob = x_cl + ((size_t)b * HWSZ + p0) * 64;
    for (int i = t; i < 512; i += 256) {
      int p = i >> 3, g = i & 7;
      *(short8*)&ob[p * 64 + g * 8] = *(const short8*)&tmp[p][g * 8];
    }
    __syncthreads();
  }

  // ---- phase 0b: weight reorder + BN fold (single-shot, low threads) ----
  // dcn w (32x32x16 A-frag): [tap9][s4][ot2][hi2][oc32][j8]
  // om  w (32x32x16 A-frag): [kk36=tap*4+s][hi2][oc32][j8], oc>=27 zeroed
  int i0 = bf * 256 + t;  // 0..204799
  if (i0 < 36864) {
    int j = i0 & 7, oc = (i0 >> 3) & 31, hi = (i0 >> 8) & 1;
    int ot = (i0 >> 9) & 1, s = (i0 >> 10) & 3, tap = i0 >> 12;
    int src = (ot * 32 + oc) * 576 + (s * 16 + hi * 8 + j) * 9 + tap;
    w1h[i0] = f2h(wd1[src]);
    w2h[i0] = f2h(wd2[src]);
  }
  if (i0 < 18432) {
    int j = i0 & 7, oc = (i0 >> 3) & 31, hi = (i0 >> 8) & 1;
    int s = (i0 >> 9) & 3, tap = i0 >> 11;
    int src = oc * 576 + (s * 16 + hi * 8 + j) * 9 + tap;
    wo1h[i0] = (oc < 27) ? f2h(wo1[src]) : (short)0;
    wo2h[i0] = (oc < 27) ? f2h(wo2[src]) : (short)0;
  }
  if (i0 < 64) {
    float s1 = g1[i0] * rsqrtf(v1[i0] + 1e-5f);
    sc[i0]       = s1;
    sc[64 + i0]  = b1[i0] - m1[i0] * s1;
    float s2 = g2[i0] * rsqrtf(v2[i0] + 1e-5f);
    sc[128 + i0] = s2;
    sc[192 + i0] = b2[i0] - m2[i0] * s2;
  }

  gridbar(bar, 0);  // x_cl + weights globally visible

  // ---- phase 1: layer-1 dcn (f16 NHWC out) ----
  dcn_body(xt, t, blockIdx.x, blockIdx.y, blockIdx.z,
           x_cl, wo1h, b_om1, w1h, sc, sc + 64,
           nullptr, o1_cl, nullptr);

  gridbar(bar, 1);  // o1_cl globally visible

  // ---- phase 2: layer-2 dcn (+f16 residual, f32 NCHW out) ----
  dcn_body(xt, t, blockIdx.x, blockIdx.y, blockIdx.z,
           o1_cl, wo2h, b_om2, w2h, sc + 128, sc + 192,
           x_cl, nullptr, outp);
}

// ---------------------------------------------------------------------------
extern "C" void kernel_launch(void* const* d_in, const int* in_sizes, int n_in,
                              void* d_out, int out_size, void* d_ws, size_t ws_size,
                              hipStream_t stream) {
  const float* x     = (const float*)d_in[0];
  const float* w_om1 = (const float*)d_in[1];
  const float* b_om1 = (const float*)d_in[2];
  const float* w_d1  = (const float*)d_in[3];
  const float* bn1g  = (const float*)d_in[4];
  const float* bn1b  = (const float*)d_in[5];
  const float* bn1m  = (const float*)d_in[6];
  const float* bn1v  = (const float*)d_in[7];
  const float* w_om2 = (const float*)d_in[8];
  const float* b_om2 = (const float*)d_in[9];
  const float* w_d2  = (const float*)d_in[10];
  const float* bn2g  = (const float*)d_in[11];
  const float* bn2b  = (const float*)d_in[12];
  const float* bn2m  = (const float*)d_in[13];
  const float* bn2v  = (const float*)d_in[14];

  float* ws    = (float*)d_ws;
  float* sc    = ws;                       // 256 f
  short* w1h   = (short*)(ws + 256);       // 36864 halves
  short* w2h   = w1h + 36864;
  short* wo1h  = w2h + 36864;              // 18432 halves
  short* wo2h  = wo1h + 18432;
  short* x_cl  = (short*)(ws + 55552);     // 6,553,600 halves
  short* o1_cl = x_cl + 6553600;           // 6,553,600 halves
  int*   bar   = (int*)(o1_cl + 6553600);  // 2 ints (grid barrier counters)
  float* outp  = (float*)d_out;

  hipMemsetAsync(bar, 0, 2 * sizeof(int), stream);

  dim3 grid(WW / 16, HH / 8, 4);  // 800 blocks, co-resident at 4 blocks/CU
  fused_all<<<grid, dim3(256), 0, stream>>>(
      x, bn1g, bn1b, bn1m, bn1v, bn2g, bn2b, bn2m, bn2v,
      w_d1, w_d2, w_om1, w_om2, b_om1, b_om2,
      sc, w1h, w2h, wo1h, wo2h, x_cl, o1_cl, outp, bar);
}

// Round 12
// 240.668 us; speedup vs baseline: 3.3034x; 3.3034x over previous
//
#include <hip/hip_runtime.h>
#include <math.h>

#define HH 160
#define WW 160
#define HWSZ 25600
#define TR 14
#define TC 22
#define NSLOT 308   // TR*TC tile slots, margin +-3 around 16x8 px tile

typedef __attribute__((ext_vector_type(8))) short short8;
typedef __attribute__((ext_vector_type(4))) short short4v;
typedef __attribute__((ext_vector_type(8))) _Float16 half8;
typedef __attribute__((ext_vector_type(2))) _Float16 half2v;
typedef __attribute__((ext_vector_type(4))) float f32x4;

__device__ __forceinline__ short f2h(float f) {
  union { _Float16 h; short s; } u; u.h = (_Float16)f; return u.s;
}
__device__ __forceinline__ float h2f(short s) {
  union { _Float16 h; short s; } u; u.s = s; return (float)u.h;
}
__device__ __forceinline__ half2v bcast_h(short s) {
  unsigned int x = (unsigned short)s; x |= x << 16;
  union { unsigned int u; half2v h; } v; v.u = x; return v.h;
}

// ---------------------------------------------------------------------------
// pre (r0 layouts): blocks [0,1600): transpose x f32 NCHW -> f16 NHWC.
//      blocks [1600,1664): BN fold + weight reorder to 16x16 A-frag layout.
// dcn w: [f18][ot4][m16][q4][j8] = w[ot*16+m][c*9+k], kp=f*32+q*8+j
// om  w: [f18][ot2][m16][q4][j8], oc>=27 zero-padded
__global__ __launch_bounds__(256) void pre_kernel(
    const float* __restrict__ x,
    const float* __restrict__ g1, const float* __restrict__ b1,
    const float* __restrict__ m1, const float* __restrict__ v1,
    const float* __restrict__ g2, const float* __restrict__ b2,
    const float* __restrict__ m2, const float* __restrict__ v2,
    const float* __restrict__ wd1, const float* __restrict__ wd2,
    const float* __restrict__ wo1, const float* __restrict__ wo2,
    float* __restrict__ sc, short* __restrict__ wd1h, short* __restrict__ wd2h,
    short* __restrict__ wo1h, short* __restrict__ wo2h,
    short* __restrict__ xcl) {
  __shared__ short tmp[64][72];
  int t = threadIdx.x;
  int bx = blockIdx.x;
  if (bx < 1600) {
    int b = bx / 400, p0 = (bx - b * 400) * 64;
    const float* xb = x + (size_t)b * 64 * HWSZ;
    for (int i = t; i < 4096; i += 256) {
      int c = i >> 6, p = i & 63;
      tmp[p][c] = f2h(xb[c * HWSZ + p0 + p]);
    }
    __syncthreads();
    short* ob = xcl + ((size_t)b * HWSZ + p0) * 64;
    for (int i = t; i < 512; i += 256) {
      int p = i >> 3, g = i & 7;
      *(short8*)&ob[p * 64 + g * 8] = *(const short8*)&tmp[p][g * 8];
    }
    return;
  }
  int i0 = (bx - 1600) * 256 + t;  // 0..16383
  for (int i = i0; i < 36864; i += 16384) {
    int j = i & 7, q = (i >> 3) & 3, m = (i >> 5) & 15;
    int ot = (i >> 9) & 3, f = i >> 11;
    int kp = f * 32 + q * 8 + j;
    int k = kp >> 6, c = kp & 63;
    int src = (ot * 16 + m) * 576 + c * 9 + k;
    wd1h[i] = f2h(wd1[src]);
    wd2h[i] = f2h(wd2[src]);
  }
  for (int i = i0; i < 18432; i += 16384) {
    int j = i & 7, q = (i >> 3) & 3, m = (i >> 5) & 15;
    int ot = (i >> 9) & 1, f = i >> 10;
    int kp = f * 32 + q * 8 + j;
    int k = kp >> 6, c = kp & 63;
    int oc = ot * 16 + m;
    wo1h[i] = (oc < 27) ? f2h(wo1[oc * 576 + c * 9 + k]) : (short)0;
    wo2h[i] = (oc < 27) ? f2h(wo2[oc * 576 + c * 9 + k]) : (short)0;
  }
  if (i0 < 64) {
    float s1 = g1[i0] * rsqrtf(v1[i0] + 1e-5f);
    sc[i0]       = s1;
    sc[64 + i0]  = b1[i0] - m1[i0] * s1;
    float s2 = g2[i0] * rsqrtf(v2[i0] + 1e-5f);
    sc[128 + i0] = s2;
    sc[192 + i0] = b2[i0] - m2[i0] * s2;
  }
}

// ---------------------------------------------------------------------------
// dcn_fused: offset-conv (27ch) + modulated deform conv (64->64) + BN
//            + optional residual + GELU, all from one staged tile.
// Block: 16x * 8y px, 512 thr / 8 waves, 16x16x32 MFMA. Wave w owns pixel
// row y0+w (16 px, 4 lanes/px). Doubles resident waves vs the 32x32 shape:
// LDS = xt 39424 + om scratch 7168 = 46592 B -> 3 blocks/CU = 24 waves/CU
// (vs 12.5), 768/800 blocks co-resident, 4% tail. Tap loop is BARRIER-FREE:
// A-frags read directly from global (whd 72 KB, L1/L2-resident); om scratch
// is wave-private (wave writes/reads only its own 16 px rows) -> whole
// kernel has ONE barrier (post-stage). Wave-local lgkmcnt drain + wave
// barrier order the scratch writes against the cross-lane register pull.
__global__ __launch_bounds__(512, 6) void dcn_fused(
    const short* __restrict__ xcl,     // [B][HW][64] f16 NHWC
    const short* __restrict__ who,     // om weights  [f18][ot2][m16][q4][j8]
    const float* __restrict__ bias_om, // 27
    const short* __restrict__ whd,     // dcn weights [f18][ot4][m16][q4][j8]
    const float* __restrict__ scale, const float* __restrict__ shift,
    const short* __restrict__ id_cl,     // f16 NHWC residual or null
    short* __restrict__ out_cl,          // f16 NHWC (layer 1) or null
    float* __restrict__ out_f32) {       // f32 NCHW (layer 2) or null
  __shared__ short xt[NSLOT * 64];          // 39424 B, 16B groups swizzled
  __shared__ __align__(16) short oms[3584]; // om scratch 128px x 28ch (7168 B)

  int t = threadIdx.x;
  int x0 = blockIdx.x * 16, y0 = blockIdx.y * 8, b = blockIdx.z;
  int w = t >> 6, lane = t & 63, q = lane >> 4, m = lane & 15;
  int ybase = y0 - 3, xbase = x0 - 3;

  // ---- stage tile (coalesced b128 copies) ----
  const short* xb = xcl + (size_t)b * HWSZ * 64;
  for (int i = t; i < NSLOT * 8; i += 512) {
    int slot = i >> 3, g = i & 7;
    int ty = slot / TC, tx = slot - ty * TC;
    int gy = ybase + ty, gx = xbase + tx;
    short8 v = {};
    if (gy >= 0 && gy < HH && gx >= 0 && gx < WW)
      v = *(const short8*)&xb[(gy * WW + gx) * 64 + g * 8];
    *(short8*)&xt[slot * 64 + ((g ^ (slot & 7)) << 3)] = v;
  }
  __syncthreads();  // xt visible -- the ONLY block barrier

  // ---- om GEMM (16x16x32): wave w -> 27 oc x 16 px of row y0+w ----
  // D col = m = px, row = q*4+r. Scratch rows are wave-private (px row
  // w*16+m written and read only by wave w) -> no block barrier needed.
  {
    f32x4 oacc0 = {}, oacc1 = {};
#pragma unroll 6
    for (int f = 0; f < 18; f++) {
      int k = f >> 1;
      int ki = k / 3, kj = k - ki * 3;
      int g = (f & 1) * 4 + q;
      int slotb = (w + ki + 2) * TC + (m + kj + 2);
      short8 bv = *(const short8*)&xt[slotb * 64 + ((g ^ (slotb & 7)) << 3)];
      const short* ap = who + (f * 128 + m * 4 + q) * 8;
      short8 a0 = *(const short8*)ap;
      short8 a1 = *(const short8*)(ap + 512);
      union { short8 s8; half8 h; } A0, A1, B;
      A0.s8 = a0; A1.s8 = a1; B.s8 = bv;
      oacc0 = __builtin_amdgcn_mfma_f32_16x16x32_f16(A0.h, B.h, oacc0, 0, 0, 0);
      oacc1 = __builtin_amdgcn_mfma_f32_16x16x32_f16(A1.h, B.h, oacc1, 0, 0, 0);
    }
    int px = w * 16 + m;
#pragma unroll
    for (int mt = 0; mt < 2; mt++) {
      f32x4 oa = mt ? oacc1 : oacc0;
      short4v pv;
#pragma unroll
      for (int r = 0; r < 4; r++) {
        int oc = mt * 16 + q * 4 + r;
        float bb = (oc < 27) ? bias_om[oc] : 0.f;
        pv[r] = f2h(oa[r] + bb);
      }
      if (mt == 0 || q != 3)  // oc 28..31 would overflow the 28-ch row
        *(short4v*)&oms[px * 28 + mt * 16 + q * 4] = pv;
    }
  }

  // wave-local ordering: drain this wave's LDS writes, pin compiler order
  asm volatile("s_waitcnt lgkmcnt(0)" ::: "memory");
  __builtin_amdgcn_wave_barrier();

  // ---- pull this lane's pixel om values (27 ch) into registers ----
  // same-wave producer; 4 q-lanes read same row -> broadcast, no conflict
  union { short s[28]; short4v v4[7]; } omr;
  {
    int px = w * 16 + m;
#pragma unroll
    for (int i = 0; i < 7; i++)
      omr.v4[i] = *(const short4v*)&oms[px * 28 + i * 4];
  }

  int y = y0 + w, x = x0 + m;

  // hoist layer-2 residual load above the tap loop (hides HBM latency)
  short4v ivs[4];
  if (out_f32) {
    size_t pbase = ((size_t)b * HWSZ + y * WW + x) * 64;
#pragma unroll
    for (int ot = 0; ot < 4; ot++)
      ivs[ot] = *(const short4v*)&id_cl[pbase + ot * 16 + q * 4];
  }

  // ---- main GEMM (16x16x32): 64 oc x 16 px/wave, K=576; barrier-free ----
  f32x4 acc[4] = {};
#pragma unroll
  for (int k = 0; k < 9; k++) {
    // inline meta for this lane's pixel (verbatim formulas)
    float dy = h2f(omr.s[2 * k]);
    float dx = h2f(omr.s[2 * k + 1]);
    float ml = h2f(omr.s[18 + k]);
    float msk = 1.f / (1.f + __expf(-ml));
    int ki = k / 3, kj = k - ki * 3;
    float py  = (float)(y - 1 + ki) + dy;
    float pxf = (float)(x - 1 + kj) + dx;
    float fy = floorf(py), fx = floorf(pxf);
    float ly = py - fy, lx = pxf - fx;
    int yi0 = (int)fy, xi0 = (int)fx;
    bool vy0 = (yi0 >= 0) & (yi0 < HH), vy1 = (yi0 + 1 >= 0) & (yi0 + 1 < HH);
    bool vx0 = (xi0 >= 0) & (xi0 < WW), vx1 = (xi0 + 1 >= 0) & (xi0 + 1 < WW);
    int ty0 = min(max(yi0 - ybase, 0), TR - 2);
    int tx0 = min(max(xi0 - xbase, 0), TC - 2);
    int p00 = ty0 * TC + tx0;
    half2v w00 = bcast_h(f2h((vy0 & vx0) ? (1.f - ly) * (1.f - lx) * msk : 0.f));
    half2v w01 = bcast_h(f2h((vy0 & vx1) ? (1.f - ly) * lx * msk : 0.f));
    half2v w10 = bcast_h(f2h((vy1 & vx0) ? ly * (1.f - lx) * msk : 0.f));
    half2v w11 = bcast_h(f2h((vy1 & vx1) ? ly * lx * msk : 0.f));
    int s00 = p00, s01 = p00 + 1, s10 = p00 + TC, s11 = p00 + TC + 1;
#pragma unroll
    for (int ch = 0; ch < 2; ch++) {
      int g = ch * 4 + q;
      // A-frags straight from global: wave covers 1KB contiguous per load,
      // whd (72 KB) is L1/L2-resident and shared by all blocks
      const short* ap = whd + (2 * k + ch) * 2048 + m * 32 + q * 8;
      short8 a0 = *(const short8*)ap;
      short8 a1 = *(const short8*)(ap + 512);
      short8 a2 = *(const short8*)(ap + 1024);
      short8 a3 = *(const short8*)(ap + 1536);
      union { short8 s8; half2v h[4]; } c00, c01, c10, c11, bb;
      c00.s8 = *(const short8*)&xt[s00 * 64 + ((g ^ (s00 & 7)) << 3)];
      c01.s8 = *(const short8*)&xt[s01 * 64 + ((g ^ (s01 & 7)) << 3)];
      c10.s8 = *(const short8*)&xt[s10 * 64 + ((g ^ (s10 & 7)) << 3)];
      c11.s8 = *(const short8*)&xt[s11 * 64 + ((g ^ (s11 & 7)) << 3)];
#pragma unroll
      for (int d = 0; d < 4; d++)
        bb.h[d] = c00.h[d] * w00 + c01.h[d] * w01 + c10.h[d] * w10 +
                  c11.h[d] * w11;
      union { short8 s8; half8 h8; } B, A0, A1, A2, A3;
      B.s8 = bb.s8; A0.s8 = a0; A1.s8 = a1; A2.s8 = a2; A3.s8 = a3;
      acc[0] = __builtin_amdgcn_mfma_f32_16x16x32_f16(A0.h8, B.h8, acc[0], 0, 0, 0);
      acc[1] = __builtin_amdgcn_mfma_f32_16x16x32_f16(A1.h8, B.h8, acc[1], 0, 0, 0);
      acc[2] = __builtin_amdgcn_mfma_f32_16x16x32_f16(A2.h8, B.h8, acc[2], 0, 0, 0);
      acc[3] = __builtin_amdgcn_mfma_f32_16x16x32_f16(A3.h8, B.h8, acc[3], 0, 0, 0);
    }
  }

  // ---- epilogue ----
  // D layout: acc[ot] = oc tile ot; oc = ot*16 + q*4 + r; px col = m
  if (out_f32) {  // layer 2: BN + residual (f16 NHWC) + GELU -> f32 NCHW
#pragma unroll
    for (int ot = 0; ot < 4; ot++) {
#pragma unroll
      for (int r = 0; r < 4; r++) {
        int oc = ot * 16 + q * 4 + r;
        size_t idx = ((size_t)(b * 64 + oc)) * HWSZ + y * WW + x;
        float v = acc[ot][r] * scale[oc] + shift[oc] + h2f(ivs[ot][r]);
        v = 0.5f * v * (1.f + erff(v * 0.70710678118654752f));
        out_f32[idx] = v;
      }
    }
  } else {  // layer 1: BN + GELU -> f16 NHWC
    size_t base = ((size_t)b * HWSZ + y * WW + x) * 64;
#pragma unroll
    for (int ot = 0; ot < 4; ot++) {
      short4v pv;
#pragma unroll
      for (int r = 0; r < 4; r++) {
        int oc = ot * 16 + q * 4 + r;
        float v = acc[ot][r] * scale[oc] + shift[oc];
        v = 0.5f * v * (1.f + erff(v * 0.70710678118654752f));
        pv[r] = f2h(v);
      }
      *(short4v*)&out_cl[base + ot * 16 + q * 4] = pv;
    }
  }
}

// ---------------------------------------------------------------------------
extern "C" void kernel_launch(void* const* d_in, const int* in_sizes, int n_in,
                              void* d_out, int out_size, void* d_ws, size_t ws_size,
                              hipStream_t stream) {
  const float* x     = (const float*)d_in[0];
  const float* w_om1 = (const float*)d_in[1];
  const float* b_om1 = (const float*)d_in[2];
  const float* w_d1  = (const float*)d_in[3];
  const float* bn1g  = (const float*)d_in[4];
  const float* bn1b  = (const float*)d_in[5];
  const float* bn1m  = (const float*)d_in[6];
  const float* bn1v  = (const float*)d_in[7];
  const float* w_om2 = (const float*)d_in[8];
  const float* b_om2 = (const float*)d_in[9];
  const float* w_d2  = (const float*)d_in[10];
  const float* bn2g  = (const float*)d_in[11];
  const float* bn2b  = (const float*)d_in[12];
  const float* bn2m  = (const float*)d_in[13];
  const float* bn2v  = (const float*)d_in[14];

  float* ws    = (float*)d_ws;
  float* sc    = ws;                       // 256 f
  short* w1h   = (short*)(ws + 256);       // 36864 halves
  short* w2h   = w1h + 36864;
  short* wo1h  = w2h + 36864;              // 18432 halves
  short* wo2h  = wo1h + 18432;
  short* x_cl  = (short*)(ws + 55552);     // 6,553,600 halves
  short* o1_cl = x_cl + 6553600;           // 6,553,600 halves
  float* outp  = (float*)d_out;

  pre_kernel<<<dim3(1664), dim3(256), 0, stream>>>(
      x, bn1g, bn1b, bn1m, bn1v, bn2g, bn2b, bn2m, bn2v,
      w_d1, w_d2, w_om1, w_om2, sc, w1h, w2h, wo1h, wo2h, x_cl);

  dim3 grid(WW / 16, HH / 8, 4);
  dcn_fused<<<grid, dim3(512), 0, stream>>>(
      x_cl, wo1h, b_om1, w1h, sc, sc + 64, nullptr, o1_cl, nullptr);
  dcn_fused<<<grid, dim3(512), 0, stream>>>(
      o1_cl, wo2h, b_om2, w2h, sc + 128, sc + 192, x_cl, nullptr, outp);
}

// Round 13
// 189.898 us; speedup vs baseline: 4.1866x; 1.2674x over previous
//
#include <hip/hip_runtime.h>
#include <math.h>

#define HH 160
#define WW 160
#define HWSZ 25600
#define TR 14
#define TC 22
#define NSLOT 308   // TR*TC tile slots, margin +-3 around 16x8 px tile

typedef __attribute__((ext_vector_type(8))) short short8;
typedef __attribute__((ext_vector_type(4))) short short4v;
typedef __attribute__((ext_vector_type(8))) _Float16 half8;
typedef __attribute__((ext_vector_type(2))) _Float16 half2v;
typedef __attribute__((ext_vector_type(4))) float f32x4;
typedef __attribute__((ext_vector_type(16))) float f32x16;
typedef __attribute__((ext_vector_type(2))) unsigned int uint2v;

__device__ __forceinline__ short f2h(float f) {
  union { _Float16 h; short s; } u; u.h = (_Float16)f; return u.s;
}
__device__ __forceinline__ float h2f(short s) {
  union { _Float16 h; short s; } u; u.s = s; return (float)u.h;
}
__device__ __forceinline__ half2v bcast_h(short s) {
  unsigned int x = (unsigned short)s; x |= x << 16;
  union { unsigned int u; half2v h; } v; v.u = x; return v.h;
}
// xt swizzle: bank quad was (g ^ (slot&7)) -> lanes m,m+8 (dslot=8) collided.
// Mixing slot>>3 in flips the quad across 8-slot strides; still a bijective
// per-slot XOR of the 8 16B-groups (write & read use the same f).
__device__ __forceinline__ int swz(int slot, int g) {
  return (g ^ ((slot ^ (slot >> 3)) & 7)) << 3;
}

// ---------------------------------------------------------------------------
// pre: blocks [0,1600): transpose x f32 NCHW -> f16 NHWC.
//      blocks [1600,1664): BN fold + weight reorder to A-frag layouts.
// dcn w (32x32x16 A-frag): [tap9][s4][ot2][hi2][oc32][j8]
// om  w (32x32x16 A-frag): [kk36=tap*4+s][hi2][oc32][j8], oc>=27 zeroed
__global__ __launch_bounds__(256) void pre_kernel(
    const float* __restrict__ x,
    const float* __restrict__ g1, const float* __restrict__ b1,
    const float* __restrict__ m1, const float* __restrict__ v1,
    const float* __restrict__ g2, const float* __restrict__ b2,
    const float* __restrict__ m2, const float* __restrict__ v2,
    const float* __restrict__ wd1, const float* __restrict__ wd2,
    const float* __restrict__ wo1, const float* __restrict__ wo2,
    float* __restrict__ sc, short* __restrict__ wd1h, short* __restrict__ wd2h,
    short* __restrict__ wo1h, short* __restrict__ wo2h,
    short* __restrict__ xcl) {
  __shared__ short tmp[64][72];
  int t = threadIdx.x;
  int bx = blockIdx.x;
  if (bx < 1600) {
    int b = bx / 400, p0 = (bx - b * 400) * 64;
    const float* xb = x + (size_t)b * 64 * HWSZ;
    for (int i = t; i < 4096; i += 256) {
      int c = i >> 6, p = i & 63;
      tmp[p][c] = f2h(xb[c * HWSZ + p0 + p]);
    }
    __syncthreads();
    short* ob = xcl + ((size_t)b * HWSZ + p0) * 64;
    for (int i = t; i < 512; i += 256) {
      int p = i >> 3, g = i & 7;
      *(short8*)&ob[p * 64 + g * 8] = *(const short8*)&tmp[p][g * 8];
    }
    return;
  }
  int i0 = (bx - 1600) * 256 + t;  // 0..16383
  for (int i = i0; i < 36864; i += 16384) {
    int j = i & 7, oc = (i >> 3) & 31, hi = (i >> 8) & 1;
    int ot = (i >> 9) & 1, s = (i >> 10) & 3, tap = i >> 12;
    int src = (ot * 32 + oc) * 576 + (s * 16 + hi * 8 + j) * 9 + tap;
    wd1h[i] = f2h(wd1[src]);
    wd2h[i] = f2h(wd2[src]);
  }
  for (int i = i0; i < 18432; i += 16384) {
    int j = i & 7, oc = (i >> 3) & 31, hi = (i >> 8) & 1;
    int s = (i >> 9) & 3, tap = i >> 11;
    int src = oc * 576 + (s * 16 + hi * 8 + j) * 9 + tap;
    wo1h[i] = (oc < 27) ? f2h(wo1[src]) : (short)0;
    wo2h[i] = (oc < 27) ? f2h(wo2[src]) : (short)0;
  }
  if (i0 < 64) {
    float s1 = g1[i0] * rsqrtf(v1[i0] + 1e-5f);
    sc[i0]       = s1;
    sc[64 + i0]  = b1[i0] - m1[i0] * s1;
    float s2 = g2[i0] * rsqrtf(v2[i0] + 1e-5f);
    sc[128 + i0] = s2;
    sc[192 + i0] = b2[i0] - m2[i0] * s2;
  }
}

// ---------------------------------------------------------------------------
// dcn_fused (r8 structure): offset-conv (27ch) + modulated deform conv
// (64->64) + BN + optional residual + GELU, all from one staged tile.
// Block: 16x * 8y px, 256 thr / 4 waves, all GEMMs 32x32x16.
// om D-col = owner pixel lane; permlane32_swap fetches the complementary
// oc-half; A-frags direct from global (L1/L2-resident); ONE barrier.
// r13 deltas vs r8: (1) two-level xt swizzle (conflict fix), (2) setprio(1)
// around MFMA pairs (free-running waves -> scheduler favors matrix pipe).
__global__ __launch_bounds__(256, 4) void dcn_fused(
    const short* __restrict__ xcl,     // [B][HW][64] f16 NHWC
    const short* __restrict__ who,     // om weights  [kk36][hi2][oc32][j8]
    const float* __restrict__ bias_om, // 27
    const short* __restrict__ whd,     // dcn weights [tap][s][ot][hi][oc][j]
    const float* __restrict__ scale, const float* __restrict__ shift,
    const short* __restrict__ id_cl,     // f16 NHWC residual or null
    short* __restrict__ out_cl,          // f16 NHWC (layer 1) or null
    float* __restrict__ out_f32) {       // f32 NCHW (layer 2) or null
  __shared__ short xt[NSLOT * 64];          // 39424 B, 16B groups swizzled

  int t = threadIdx.x;
  int x0 = blockIdx.x * 16, y0 = blockIdx.y * 8, b = blockIdx.z;
  int w = t >> 6, lane = t & 63, m = lane & 15;
  int hi = lane >> 5, p31 = lane & 31;
  int ybase = y0 - 3, xbase = x0 - 3;

  // ---- stage tile (coalesced b128 copies) ----
  const short* xb = xcl + (size_t)b * HWSZ * 64;
  for (int i = t; i < NSLOT * 8; i += 256) {
    int slot = i >> 3, g = i & 7;
    int ty = slot / TC, tx = slot - ty * TC;
    int gy = ybase + ty, gx = xbase + tx;
    short8 v = {};
    if (gy >= 0 && gy < HH && gx >= 0 && gx < WW)
      v = *(const short8*)&xb[(gy * WW + gx) * 64 + g * 8];
    *(short8*)&xt[slot * 64 + swz(slot, g)] = v;
  }
  __syncthreads();  // xt visible -- the ONLY barrier

  // ---- om GEMM (32x32x16): 27 oc x 32 px per wave, D col = own pixel ----
  union { short s[32]; unsigned int u[16]; } omr;
  {
    f32x16 oacc = {};
#pragma unroll
    for (int k9 = 0; k9 < 9; k9++) {
      int ki = k9 / 3, kj = k9 - ki * 3;
      int slotb = (w * 2 + (p31 >> 4) + ki + 2) * TC + ((p31 & 15) + kj + 2);
#pragma unroll
      for (int s = 0; s < 4; s++) {
        int g = s * 2 + hi;
        union { short8 s8; half8 h; } A, B;
        B.s8 = *(const short8*)&xt[slotb * 64 + swz(slotb, g)];
        A.s8 = *(const short8*)&who[((k9 * 4 + s) * 64 + lane) * 8];
        __builtin_amdgcn_s_setprio(1);
        oacc = __builtin_amdgcn_mfma_f32_32x32x16_f16(A.h, B.h, oacc, 0, 0, 0);
        __builtin_amdgcn_s_setprio(0);
      }
    }
#pragma unroll
    for (int j = 0; j < 8; j++) {
      int c0 = 2 * (j & 1) + 8 * (j >> 1);  // channel pair base for hi=0
      int oc0 = c0 + 4 * hi;                // this lane's oc for r=2j
      float b0 = (oc0 < 27) ? bias_om[oc0] : 0.f;
      float b1 = (oc0 + 1 < 27) ? bias_om[oc0 + 1] : 0.f;
      union { unsigned int u; short s2[2]; } pk;
      pk.s2[0] = f2h(oacc[2 * j] + b0);
      pk.s2[1] = f2h(oacc[2 * j + 1] + b1);
      uint2v sw = __builtin_amdgcn_permlane32_swap(pk.u, pk.u, false, false);
      omr.u[c0 >> 1]       = sw[0];
      omr.u[(c0 + 4) >> 1] = sw[1];
    }
  }

  int y = y0 + w * 2 + (p31 >> 4), x = x0 + m;

  // hoist layer-2 residual load above the tap loop (hides HBM latency)
  short4v ivs[8];
  if (out_f32) {
    size_t pbase = ((size_t)b * HWSZ + y * WW + x) * 64;
#pragma unroll
    for (int ot = 0; ot < 2; ot++)
#pragma unroll
      for (int blk = 0; blk < 4; blk++)
        ivs[ot * 4 + blk] =
            *(const short4v*)&id_cl[pbase + ot * 32 + blk * 8 + hi * 4];
  }

  // ---- main GEMM (32x32x16): 64 oc x 32 px/wave, K=576; barrier-free ----
  f32x16 acc0 = {}, acc1 = {};
#pragma unroll
  for (int k = 0; k < 9; ++k) {
    // inline meta for this lane's pixel (verbatim formulas)
    float dy = h2f(omr.s[2 * k]);
    float dx = h2f(omr.s[2 * k + 1]);
    float ml = h2f(omr.s[18 + k]);
    float msk = 1.f / (1.f + __expf(-ml));
    int ki = k / 3, kj = k - ki * 3;
    float py  = (float)(y - 1 + ki) + dy;
    float pxf = (float)(x - 1 + kj) + dx;
    float fy = floorf(py), fx = floorf(pxf);
    float ly = py - fy, lx = pxf - fx;
    int yi0 = (int)fy, xi0 = (int)fx;
    bool vy0 = (yi0 >= 0) & (yi0 < HH), vy1 = (yi0 + 1 >= 0) & (yi0 + 1 < HH);
    bool vx0 = (xi0 >= 0) & (xi0 < WW), vx1 = (xi0 + 1 >= 0) & (xi0 + 1 < WW);
    int ty0 = min(max(yi0 - ybase, 0), TR - 2);
    int tx0 = min(max(xi0 - xbase, 0), TC - 2);
    int p00 = ty0 * TC + tx0;
    half2v w00 = bcast_h(f2h((vy0 & vx0) ? (1.f - ly) * (1.f - lx) * msk : 0.f));
    half2v w01 = bcast_h(f2h((vy0 & vx1) ? (1.f - ly) * lx * msk : 0.f));
    half2v w10 = bcast_h(f2h((vy1 & vx0) ? ly * (1.f - lx) * msk : 0.f));
    half2v w11 = bcast_h(f2h((vy1 & vx1) ? ly * lx * msk : 0.f));
    int s00 = p00, s01 = p00 + 1, s10 = p00 + TC, s11 = p00 + TC + 1;
#pragma unroll
    for (int s = 0; s < 4; s++) {
      int g = s * 2 + hi;  // 16B ch-group this lane consumes for slice s
      union { short8 s8; half2v h[4]; } c00, c01, c10, c11, bb;
      c00.s8 = *(const short8*)&xt[s00 * 64 + swz(s00, g)];
      c01.s8 = *(const short8*)&xt[s01 * 64 + swz(s01, g)];
      c10.s8 = *(const short8*)&xt[s10 * 64 + swz(s10, g)];
      c11.s8 = *(const short8*)&xt[s11 * 64 + swz(s11, g)];
#pragma unroll
      for (int d = 0; d < 4; d++)
        bb.h[d] = c00.h[d] * w00 + c01.h[d] * w01 + c10.h[d] * w10 +
                  c11.h[d] * w11;
      // A-frags straight from global: 1KB contiguous per wave read,
      // whd (72 KB) is L1/L2-resident and shared by all blocks
      const short* ap = whd + k * 4096 + s * 1024 + lane * 8;
      short8 a0 = *(const short8*)ap;
      short8 a1 = *(const short8*)(ap + 512);
      union { short8 s8; half8 h8; } B, A0, A1;
      B.s8 = bb.s8; A0.s8 = a0; A1.s8 = a1;
      __builtin_amdgcn_s_setprio(1);
      acc0 = __builtin_amdgcn_mfma_f32_32x32x16_f16(A0.h8, B.h8, acc0, 0, 0, 0);
      acc1 = __builtin_amdgcn_mfma_f32_32x32x16_f16(A1.h8, B.h8, acc1, 0, 0, 0);
      __builtin_amdgcn_s_setprio(0);
    }
  }

  // ---- epilogue ----
  // D layout (32x32): col px = lane&31; row oc_in_tile = (r&3)+8*(r>>2)+4*hi
  if (out_f32) {  // layer 2: BN + residual (f16 NHWC) + GELU -> f32 NCHW
#pragma unroll
    for (int ot = 0; ot < 2; ot++) {
#pragma unroll
      for (int r = 0; r < 16; r++) {
        int oc = ot * 32 + (r & 3) + 8 * (r >> 2) + 4 * hi;
        float a = ot ? acc1[r] : acc0[r];
        size_t idx = ((size_t)(b * 64 + oc)) * HWSZ + y * WW + x;
        float v = a * scale[oc] + shift[oc] + h2f(ivs[ot * 4 + (r >> 2)][r & 3]);
        v = 0.5f * v * (1.f + erff(v * 0.70710678118654752f));
        out_f32[idx] = v;
      }
    }
  } else {  // layer 1: BN + GELU -> f16 NHWC
    size_t base = ((size_t)b * HWSZ + y * WW + x) * 64;
#pragma unroll
    for (int ot = 0; ot < 2; ot++) {
#pragma unroll
      for (int blk = 0; blk < 4; blk++) {
        short4v pv;
#pragma unroll
        for (int rr = 0; rr < 4; rr++) {
          int r = blk * 4 + rr;
          int oc = ot * 32 + blk * 8 + hi * 4 + rr;
          float a = ot ? acc1[r] : acc0[r];
          float v = a * scale[oc] + shift[oc];
          v = 0.5f * v * (1.f + erff(v * 0.70710678118654752f));
          pv[rr] = f2h(v);
        }
        *(short4v*)&out_cl[base + ot * 32 + blk * 8 + hi * 4] = pv;
      }
    }
  }
}

// ---------------------------------------------------------------------------
extern "C" void kernel_launch(void* const* d_in, const int* in_sizes, int n_in,
                              void* d_out, int out_size, void* d_ws, size_t ws_size,
                              hipStream_t stream) {
  const float* x     = (const float*)d_in[0];
  const float* w_om1 = (const float*)d_in[1];
  const float* b_om1 = (const float*)d_in[2];
  const float* w_d1  = (const float*)d_in[3];
  const float* bn1g  = (const float*)d_in[4];
  const float* bn1b  = (const float*)d_in[5];
  const float* bn1m  = (const float*)d_in[6];
  const float* bn1v  = (const float*)d_in[7];
  const float* w_om2 = (const float*)d_in[8];
  const float* b_om2 = (const float*)d_in[9];
  const float* w_d2  = (const float*)d_in[10];
  const float* bn2g  = (const float*)d_in[11];
  const float* bn2b  = (const float*)d_in[12];
  const float* bn2m  = (const float*)d_in[13];
  const float* bn2v  = (const float*)d_in[14];

  float* ws    = (float*)d_ws;
  float* sc    = ws;                       // 256 f
  short* w1h   = (short*)(ws + 256);       // 36864 halves
  short* w2h   = w1h + 36864;
  short* wo1h  = w2h + 36864;              // 18432 halves
  short* wo2h  = wo1h + 18432;
  short* x_cl  = (short*)(ws + 55552);     // 6,553,600 halves
  short* o1_cl = x_cl + 6553600;           // 6,553,600 halves
  float* outp  = (float*)d_out;

  pre_kernel<<<dim3(1664), dim3(256), 0, stream>>>(
      x, bn1g, bn1b, bn1m, bn1v, bn2g, bn2b, bn2m, bn2v,
      w_d1, w_d2, w_om1, w_om2, sc, w1h, w2h, wo1h, wo2h, x_cl);

  dim3 grid(WW / 16, HH / 8, 4);
  dcn_fused<<<grid, dim3(256), 0, stream>>>(
      x_cl, wo1h, b_om1, w1h, sc, sc + 64, nullptr, o1_cl, nullptr);
  dcn_fused<<<grid, dim3(256), 0, stream>>>(
      o1_cl, wo2h, b_om2, w2h, sc + 128, sc + 192, x_cl, nullptr, outp);
}

// Round 14
// 182.441 us; speedup vs baseline: 4.3577x; 1.0409x over previous
//
#include <hip/hip_runtime.h>
#include <math.h>

#define HH 160
#define WW 160
#define HWSZ 25600
#define TR 14
#define TC 22
#define NSLOT 308   // TR*TC tile slots, margin +-3 around 16x8 px tile

typedef __attribute__((ext_vector_type(8))) short short8;
typedef __attribute__((ext_vector_type(4))) short short4v;
typedef __attribute__((ext_vector_type(8))) _Float16 half8;
typedef __attribute__((ext_vector_type(2))) _Float16 half2v;
typedef __attribute__((ext_vector_type(4))) float f32x4;
typedef __attribute__((ext_vector_type(16))) float f32x16;
typedef __attribute__((ext_vector_type(2))) unsigned int uint2v;

__device__ __forceinline__ short f2h(float f) {
  union { _Float16 h; short s; } u; u.h = (_Float16)f; return u.s;
}
__device__ __forceinline__ float h2f(short s) {
  union { _Float16 h; short s; } u; u.s = s; return (float)u.h;
}
__device__ __forceinline__ half2v bcast_h(short s) {
  unsigned int x = (unsigned short)s; x |= x << 16;
  union { unsigned int u; half2v h; } v; v.u = x; return v.h;
}
// xt swizzle: bank quad was (g ^ (slot&7)) -> lanes m,m+8 (dslot=8) collided.
// Mixing slot>>3 in flips the quad across 8-slot strides; still a bijective
// per-slot XOR of the 8 16B-groups (write & read use the same f).
// [r13 A/B: this alone cut SQ_LDS_BANK_CONFLICT 4.6M->3.35M]
__device__ __forceinline__ int swz(int slot, int g) {
  return (g ^ ((slot ^ (slot >> 3)) & 7)) << 3;
}

// ---------------------------------------------------------------------------
// pre: blocks [0,1600): transpose x f32 NCHW -> f16 NHWC.
//      blocks [1600,1664): BN fold + weight reorder to A-frag layouts.
// dcn w (32x32x16 A-frag): [tap9][s4][ot2][hi2][oc32][j8]
// om  w (32x32x16 A-frag): [kk36=tap*4+s][hi2][oc32][j8], oc>=27 zeroed
__global__ __launch_bounds__(256) void pre_kernel(
    const float* __restrict__ x,
    const float* __restrict__ g1, const float* __restrict__ b1,
    const float* __restrict__ m1, const float* __restrict__ v1,
    const float* __restrict__ g2, const float* __restrict__ b2,
    const float* __restrict__ m2, const float* __restrict__ v2,
    const float* __restrict__ wd1, const float* __restrict__ wd2,
    const float* __restrict__ wo1, const float* __restrict__ wo2,
    float* __restrict__ sc, short* __restrict__ wd1h, short* __restrict__ wd2h,
    short* __restrict__ wo1h, short* __restrict__ wo2h,
    short* __restrict__ xcl) {
  __shared__ short tmp[64][72];
  int t = threadIdx.x;
  int bx = blockIdx.x;
  if (bx < 1600) {
    int b = bx / 400, p0 = (bx - b * 400) * 64;
    const float* xb = x + (size_t)b * 64 * HWSZ;
    for (int i = t; i < 4096; i += 256) {
      int c = i >> 6, p = i & 63;
      tmp[p][c] = f2h(xb[c * HWSZ + p0 + p]);
    }
    __syncthreads();
    short* ob = xcl + ((size_t)b * HWSZ + p0) * 64;
    for (int i = t; i < 512; i += 256) {
      int p = i >> 3, g = i & 7;
      *(short8*)&ob[p * 64 + g * 8] = *(const short8*)&tmp[p][g * 8];
    }
    return;
  }
  int i0 = (bx - 1600) * 256 + t;  // 0..16383
  for (int i = i0; i < 36864; i += 16384) {
    int j = i & 7, oc = (i >> 3) & 31, hi = (i >> 8) & 1;
    int ot = (i >> 9) & 1, s = (i >> 10) & 3, tap = i >> 12;
    int src = (ot * 32 + oc) * 576 + (s * 16 + hi * 8 + j) * 9 + tap;
    wd1h[i] = f2h(wd1[src]);
    wd2h[i] = f2h(wd2[src]);
  }
  for (int i = i0; i < 18432; i += 16384) {
    int j = i & 7, oc = (i >> 3) & 31, hi = (i >> 8) & 1;
    int s = (i >> 9) & 3, tap = i >> 11;
    int src = oc * 576 + (s * 16 + hi * 8 + j) * 9 + tap;
    wo1h[i] = (oc < 27) ? f2h(wo1[src]) : (short)0;
    wo2h[i] = (oc < 27) ? f2h(wo2[src]) : (short)0;
  }
  if (i0 < 64) {
    float s1 = g1[i0] * rsqrtf(v1[i0] + 1e-5f);
    sc[i0]       = s1;
    sc[64 + i0]  = b1[i0] - m1[i0] * s1;
    float s2 = g2[i0] * rsqrtf(v2[i0] + 1e-5f);
    sc[128 + i0] = s2;
    sc[192 + i0] = b2[i0] - m2[i0] * s2;
  }
}

// ---------------------------------------------------------------------------
// dcn_fused (r8 structure + r13 swizzle, setprio REMOVED): offset-conv
// (27ch) + modulated deform conv (64->64) + BN + optional residual + GELU,
// all from one staged tile. Block: 16x * 8y px, 256 thr / 4 waves, all
// GEMMs 32x32x16. om D-col = owner pixel lane; permlane32_swap fetches the
// complementary oc-half; A-frags direct from global (L1/L2-resident);
// ONE barrier total. r13 A/B showed setprio costs ~3 us here (homogeneous
// GEMM body, no wave role-split -> T5 mechanism absent; matches m190).
__global__ __launch_bounds__(256, 4) void dcn_fused(
    const short* __restrict__ xcl,     // [B][HW][64] f16 NHWC
    const short* __restrict__ who,     // om weights  [kk36][hi2][oc32][j8]
    const float* __restrict__ bias_om, // 27
    const short* __restrict__ whd,     // dcn weights [tap][s][ot][hi][oc][j]
    const float* __restrict__ scale, const float* __restrict__ shift,
    const short* __restrict__ id_cl,     // f16 NHWC residual or null
    short* __restrict__ out_cl,          // f16 NHWC (layer 1) or null
    float* __restrict__ out_f32) {       // f32 NCHW (layer 2) or null
  __shared__ short xt[NSLOT * 64];          // 39424 B, 16B groups swizzled

  int t = threadIdx.x;
  int x0 = blockIdx.x * 16, y0 = blockIdx.y * 8, b = blockIdx.z;
  int w = t >> 6, lane = t & 63, m = lane & 15;
  int hi = lane >> 5, p31 = lane & 31;
  int ybase = y0 - 3, xbase = x0 - 3;

  // ---- stage tile (coalesced b128 copies) ----
  const short* xb = xcl + (size_t)b * HWSZ * 64;
  for (int i = t; i < NSLOT * 8; i += 256) {
    int slot = i >> 3, g = i & 7;
    int ty = slot / TC, tx = slot - ty * TC;
    int gy = ybase + ty, gx = xbase + tx;
    short8 v = {};
    if (gy >= 0 && gy < HH && gx >= 0 && gx < WW)
      v = *(const short8*)&xb[(gy * WW + gx) * 64 + g * 8];
    *(short8*)&xt[slot * 64 + swz(slot, g)] = v;
  }
  __syncthreads();  // xt visible -- the ONLY barrier

  // ---- om GEMM (32x32x16): 27 oc x 32 px per wave, D col = own pixel ----
  union { short s[32]; unsigned int u[16]; } omr;
  {
    f32x16 oacc = {};
#pragma unroll
    for (int k9 = 0; k9 < 9; k9++) {
      int ki = k9 / 3, kj = k9 - ki * 3;
      int slotb = (w * 2 + (p31 >> 4) + ki + 2) * TC + ((p31 & 15) + kj + 2);
#pragma unroll
      for (int s = 0; s < 4; s++) {
        int g = s * 2 + hi;
        union { short8 s8; half8 h; } A, B;
        B.s8 = *(const short8*)&xt[slotb * 64 + swz(slotb, g)];
        A.s8 = *(const short8*)&who[((k9 * 4 + s) * 64 + lane) * 8];
        oacc = __builtin_amdgcn_mfma_f32_32x32x16_f16(A.h, B.h, oacc, 0, 0, 0);
      }
    }
#pragma unroll
    for (int j = 0; j < 8; j++) {
      int c0 = 2 * (j & 1) + 8 * (j >> 1);  // channel pair base for hi=0
      int oc0 = c0 + 4 * hi;                // this lane's oc for r=2j
      float b0 = (oc0 < 27) ? bias_om[oc0] : 0.f;
      float b1 = (oc0 + 1 < 27) ? bias_om[oc0 + 1] : 0.f;
      union { unsigned int u; short s2[2]; } pk;
      pk.s2[0] = f2h(oacc[2 * j] + b0);
      pk.s2[1] = f2h(oacc[2 * j + 1] + b1);
      uint2v sw = __builtin_amdgcn_permlane32_swap(pk.u, pk.u, false, false);
      omr.u[c0 >> 1]       = sw[0];
      omr.u[(c0 + 4) >> 1] = sw[1];
    }
  }

  int y = y0 + w * 2 + (p31 >> 4), x = x0 + m;

  // hoist layer-2 residual load above the tap loop (hides HBM latency)
  short4v ivs[8];
  if (out_f32) {
    size_t pbase = ((size_t)b * HWSZ + y * WW + x) * 64;
#pragma unroll
    for (int ot = 0; ot < 2; ot++)
#pragma unroll
      for (int blk = 0; blk < 4; blk++)
        ivs[ot * 4 + blk] =
            *(const short4v*)&id_cl[pbase + ot * 32 + blk * 8 + hi * 4];
  }

  // ---- main GEMM (32x32x16): 64 oc x 32 px/wave, K=576; barrier-free ----
  f32x16 acc0 = {}, acc1 = {};
#pragma unroll
  for (int k = 0; k < 9; ++k) {
    // inline meta for this lane's pixel (verbatim formulas)
    float dy = h2f(omr.s[2 * k]);
    float dx = h2f(omr.s[2 * k + 1]);
    float ml = h2f(omr.s[18 + k]);
    float msk = 1.f / (1.f + __expf(-ml));
    int ki = k / 3, kj = k - ki * 3;
    float py  = (float)(y - 1 + ki) + dy;
    float pxf = (float)(x - 1 + kj) + dx;
    float fy = floorf(py), fx = floorf(pxf);
    float ly = py - fy, lx = pxf - fx;
    int yi0 = (int)fy, xi0 = (int)fx;
    bool vy0 = (yi0 >= 0) & (yi0 < HH), vy1 = (yi0 + 1 >= 0) & (yi0 + 1 < HH);
    bool vx0 = (xi0 >= 0) & (xi0 < WW), vx1 = (xi0 + 1 >= 0) & (xi0 + 1 < WW);
    int ty0 = min(max(yi0 - ybase, 0), TR - 2);
    int tx0 = min(max(xi0 - xbase, 0), TC - 2);
    int p00 = ty0 * TC + tx0;
    half2v w00 = bcast_h(f2h((vy0 & vx0) ? (1.f - ly) * (1.f - lx) * msk : 0.f));
    half2v w01 = bcast_h(f2h((vy0 & vx1) ? (1.f - ly) * lx * msk : 0.f));
    half2v w10 = bcast_h(f2h((vy1 & vx0) ? ly * (1.f - lx) * msk : 0.f));
    half2v w11 = bcast_h(f2h((vy1 & vx1) ? ly * lx * msk : 0.f));
    int s00 = p00, s01 = p00 + 1, s10 = p00 + TC, s11 = p00 + TC + 1;
#pragma unroll
    for (int s = 0; s < 4; s++) {
      int g = s * 2 + hi;  // 16B ch-group this lane consumes for slice s
      union { short8 s8; half2v h[4]; } c00, c01, c10, c11, bb;
      c00.s8 = *(const short8*)&xt[s00 * 64 + swz(s00, g)];
      c01.s8 = *(const short8*)&xt[s01 * 64 + swz(s01, g)];
      c10.s8 = *(const short8*)&xt[s10 * 64 + swz(s10, g)];
      c11.s8 = *(const short8*)&xt[s11 * 64 + swz(s11, g)];
#pragma unroll
      for (int d = 0; d < 4; d++)
        bb.h[d] = c00.h[d] * w00 + c01.h[d] * w01 + c10.h[d] * w10 +
                  c11.h[d] * w11;
      // A-frags straight from global: 1KB contiguous per wave read,
      // whd (72 KB) is L1/L2-resident and shared by all blocks
      const short* ap = whd + k * 4096 + s * 1024 + lane * 8;
      short8 a0 = *(const short8*)ap;
      short8 a1 = *(const short8*)(ap + 512);
      union { short8 s8; half8 h8; } B, A0, A1;
      B.s8 = bb.s8; A0.s8 = a0; A1.s8 = a1;
      acc0 = __builtin_amdgcn_mfma_f32_32x32x16_f16(A0.h8, B.h8, acc0, 0, 0, 0);
      acc1 = __builtin_amdgcn_mfma_f32_32x32x16_f16(A1.h8, B.h8, acc1, 0, 0, 0);
    }
  }

  // ---- epilogue ----
  // D layout (32x32): col px = lane&31; row oc_in_tile = (r&3)+8*(r>>2)+4*hi
  if (out_f32) {  // layer 2: BN + residual (f16 NHWC) + GELU -> f32 NCHW
#pragma unroll
    for (int ot = 0; ot < 2; ot++) {
#pragma unroll
      for (int r = 0; r < 16; r++) {
        int oc = ot * 32 + (r & 3) + 8 * (r >> 2) + 4 * hi;
        float a = ot ? acc1[r] : acc0[r];
        size_t idx = ((size_t)(b * 64 + oc)) * HWSZ + y * WW + x;
        float v = a * scale[oc] + shift[oc] + h2f(ivs[ot * 4 + (r >> 2)][r & 3]);
        v = 0.5f * v * (1.f + erff(v * 0.70710678118654752f));
        out_f32[idx] = v;
      }
    }
  } else {  // layer 1: BN + GELU -> f16 NHWC
    size_t base = ((size_t)b * HWSZ + y * WW + x) * 64;
#pragma unroll
    for (int ot = 0; ot < 2; ot++) {
#pragma unroll
      for (int blk = 0; blk < 4; blk++) {
        short4v pv;
#pragma unroll
        for (int rr = 0; rr < 4; rr++) {
          int r = blk * 4 + rr;
          int oc = ot * 32 + blk * 8 + hi * 4 + rr;
          float a = ot ? acc1[r] : acc0[r];
          float v = a * scale[oc] + shift[oc];
          v = 0.5f * v * (1.f + erff(v * 0.70710678118654752f));
          pv[rr] = f2h(v);
        }
        *(short4v*)&out_cl[base + ot * 32 + blk * 8 + hi * 4] = pv;
      }
    }
  }
}

// ---------------------------------------------------------------------------
extern "C" void kernel_launch(void* const* d_in, const int* in_sizes, int n_in,
                              void* d_out, int out_size, void* d_ws, size_t ws_size,
                              hipStream_t stream) {
  const float* x     = (const float*)d_in[0];
  const float* w_om1 = (const float*)d_in[1];
  const float* b_om1 = (const float*)d_in[2];
  const float* w_d1  = (const float*)d_in[3];
  const float* bn1g  = (const float*)d_in[4];
  const float* bn1b  = (const float*)d_in[5];
  const float* bn1m  = (const float*)d_in[6];
  const float* bn1v  = (const float*)d_in[7];
  const float* w_om2 = (const float*)d_in[8];
  const float* b_om2 = (const float*)d_in[9];
  const float* w_d2  = (const float*)d_in[10];
  const float* bn2g  = (const float*)d_in[11];
  const float* bn2b  = (const float*)d_in[12];
  const float* bn2m  = (const float*)d_in[13];
  const float* bn2v  = (const float*)d_in[14];

  float* ws    = (float*)d_ws;
  float* sc    = ws;                       // 256 f
  short* w1h   = (short*)(ws + 256);       // 36864 halves
  short* w2h   = w1h + 36864;
  short* wo1h  = w2h + 36864;              // 18432 halves
  short* wo2h  = wo1h + 18432;
  short* x_cl  = (short*)(ws + 55552);     // 6,553,600 halves
  short* o1_cl = x_cl + 6553600;           // 6,553,600 halves
  float* outp  = (float*)d_out;

  pre_kernel<<<dim3(1664), dim3(256), 0, stream>>>(
      x, bn1g, bn1b, bn1m, bn1v, bn2g, bn2b, bn2m, bn2v,
      w_d1, w_d2, w_om1, w_om2, sc, w1h, w2h, wo1h, wo2h, x_cl);

  dim3 grid(WW / 16, HH / 8, 4);
  dcn_fused<<<grid, dim3(256), 0, stream>>>(
      x_cl, wo1h, b_om1, w1h, sc, sc + 64, nullptr, o1_cl, nullptr);
  dcn_fused<<<grid, dim3(256), 0, stream>>>(
      o1_cl, wo2h, b_om2, w2h, sc + 128, sc + 192, x_cl, nullptr, outp);
}